// Round 2
// 469.930 us; speedup vs baseline: 1.1138x; 1.1138x over previous
//
#include <hip/hip_runtime.h>
#include <hip/hip_bf16.h>

// Bilinear sparse interpolation, two-pass with bf16 intermediate:
//  1) transpose x [B,C,Hx,Wx] fp32 -> xT [B,Hx,Wx,C] bf16 in d_ws
//     (157 MB -- fits in the 256 MB Infinity Cache). x reads are
//     non-temporal so the streamed fp32 input does not evict xT from L3.
//  2) gather: 8 channels per thread (uint4 = 16B per corner load),
//     8 lanes per point, 32 points per 256-thread block. fp32 weights,
//     fp32 out via non-temporal float4 stores (out is never re-read).
//
// R1 evidence: NCHW gather = 7x HBM over-fetch (2.12 GB).
// R2 evidence: fp32 transpose+gather = ~245us on its own roofline.
// R3 (prev best 523us): fills dominate rocprof top-5; gather was 2B-load
//     latency-bound (16KB/CU in flight) -> vectorize 8x + nt hints.
// R4: nontemporal builtin needs a clang vector type, not HIP float4.

constexpr int C_ = 64;
constexpr int Hx_ = 240;
constexpr int Wx_ = 320;
constexpr int HW_ = Hx_ * Wx_;

typedef float f32x4 __attribute__((ext_vector_type(4)));

static __device__ __forceinline__ unsigned short f2bf_raw(float v) {
  __hip_bfloat16 h = __float2bfloat16(v);
  return *reinterpret_cast<unsigned short*>(&h);
}

// bf16 raw (packed pair in a uint) -> float
static __device__ __forceinline__ float bf_lo(unsigned int w) {
  return __uint_as_float(w << 16);
}
static __device__ __forceinline__ float bf_hi(unsigned int w) {
  return __uint_as_float(w & 0xffff0000u);
}

// ---- pass 1: NCHW fp32 -> NHWC bf16 transpose -----------------------------
// block = 256 threads, tile = 64 hw x 64 c. LDS row stride 66 ushorts (132B,
// 4B-aligned, 33 dwords -> consecutive hw rows shift 1 bank).
// load : lanes vary hw -> 256B contiguous non-temporal global reads per wave
// store: ushort2 per thread, wave covers 64 consecutive pairs -> 256B stores
__global__ __launch_bounds__(256) void transpose_nchw_nhwc_bf16(
    const float* __restrict__ x, unsigned short* __restrict__ xT) {
  __shared__ unsigned short tile[64 * 66];
  const int t = threadIdx.x;
  const int hw_l = t & 63;
  const int cg = t >> 6;  // 0..3
  const int hw0 = blockIdx.x * 64;
  const int b = blockIdx.y;

  const float* xin = x + (size_t)b * C_ * HW_ + hw0;
#pragma unroll
  for (int i = 0; i < 16; ++i) {
    const int c = i * 4 + cg;
    // non-temporal: x is streamed exactly once; keep L3 for xT
    const float v = __builtin_nontemporal_load(&xin[(size_t)c * HW_ + hw_l]);
    tile[hw_l * 66 + c] = f2bf_raw(v);
  }
  __syncthreads();

  // xout viewed as uint (=2 bf16). element index = hw*32 + cpair
  unsigned int* xout =
      (unsigned int*)(xT + (size_t)b * HW_ * C_ + (size_t)hw0 * C_);
#pragma unroll
  for (int j = 0; j < 8; ++j) {
    const int idx = j * 256 + t;  // pair index 0..2047
    const int hw = idx >> 5;
    const int cp = idx & 31;
    const unsigned int pair =
        *reinterpret_cast<const unsigned int*>(&tile[hw * 66 + cp * 2]);
    xout[hw * 32 + cp] = pair;  // normal store: want xT cached in L3
  }
}

// ---- pass 2: gather from NHWC bf16, 8 channels / thread -------------------
// lane layout: c8 = t&7 (channels 8*c8..8*c8+7), point = t>>3 (32 pts/block)
// per corner: uint4 load = 16B = 8 bf16 channels; 4 corners in flight/thread
__global__ __launch_bounds__(256) void gather_nhwc_bf16_v2(
    const unsigned short* __restrict__ xT, const float* __restrict__ pos,
    const int* __restrict__ Hp, const int* __restrict__ Wp,
    float* __restrict__ out, int N) {
  const int t = threadIdx.x;
  const int c8 = t & 7;
  const int p = blockIdx.x * 32 + (t >> 3);
  const int b = blockIdx.y;
  if (p >= N) return;

  const float Wf = (float)Wp[0];
  const float Hf = (float)Hp[0];

  const float2 xy =
      *reinterpret_cast<const float2*>(pos + ((size_t)b * N + p) * 2);
  const float px = xy.x * (float)(Wx_ - 1) / Wf;
  const float py = xy.y * (float)(Hx_ - 1) / Hf;

  int x0 = min(max((int)floorf(px), 0), Wx_ - 1);
  int y0 = min(max((int)floorf(py), 0), Hx_ - 1);
  const int x1 = min(x0 + 1, Wx_ - 1);
  const int y1 = min(y0 + 1, Hx_ - 1);

  const float x0f = (float)x0, x1f = (float)x1;
  const float y0f = (float)y0, y1f = (float)y1;
  const float wa = (x1f - px) * (y1f - py);
  const float wb = (x1f - px) * (py - y0f);
  const float wc = (px - x0f) * (y1f - py);
  const float wd = (px - x0f) * (py - y0f);

  const unsigned short* bb = xT + (size_t)b * (size_t)(HW_ * C_);
  const int r0 = y0 * Wx_;
  const int r1 = y1 * Wx_;
  const int co = c8 * 8;  // channel offset within the 64-ch pixel record

  const uint4 va = *reinterpret_cast<const uint4*>(bb + (r0 + x0) * C_ + co);
  const uint4 vb = *reinterpret_cast<const uint4*>(bb + (r1 + x0) * C_ + co);
  const uint4 vc = *reinterpret_cast<const uint4*>(bb + (r0 + x1) * C_ + co);
  const uint4 vd = *reinterpret_cast<const uint4*>(bb + (r1 + x1) * C_ + co);

  f32x4 o0, o1;
  o0.x = wa * bf_lo(va.x) + wb * bf_lo(vb.x) + wc * bf_lo(vc.x) + wd * bf_lo(vd.x);
  o0.y = wa * bf_hi(va.x) + wb * bf_hi(vb.x) + wc * bf_hi(vc.x) + wd * bf_hi(vd.x);
  o0.z = wa * bf_lo(va.y) + wb * bf_lo(vb.y) + wc * bf_lo(vc.y) + wd * bf_lo(vd.y);
  o0.w = wa * bf_hi(va.y) + wb * bf_hi(vb.y) + wc * bf_hi(vc.y) + wd * bf_hi(vd.y);
  o1.x = wa * bf_lo(va.z) + wb * bf_lo(vb.z) + wc * bf_lo(vc.z) + wd * bf_lo(vd.z);
  o1.y = wa * bf_hi(va.z) + wb * bf_hi(vb.z) + wc * bf_hi(vc.z) + wd * bf_hi(vd.z);
  o1.z = wa * bf_lo(va.w) + wb * bf_lo(vb.w) + wc * bf_lo(vc.w) + wd * bf_lo(vd.w);
  o1.w = wa * bf_hi(va.w) + wb * bf_hi(vb.w) + wc * bf_hi(vc.w) + wd * bf_hi(vd.w);

  float* op = out + ((size_t)b * N + p) * C_ + co;
  // non-temporal: out is write-once, never re-read; keep L3 for xT
  __builtin_nontemporal_store(o0, reinterpret_cast<f32x4*>(op));
  __builtin_nontemporal_store(o1, reinterpret_cast<f32x4*>(op) + 1);
}

// ---- fallback (direct NCHW gather) if ws too small ------------------------
#define BQ 4  // points per block

__global__ __launch_bounds__(256) void gather_nchw_direct(
    const float* __restrict__ x, const float* __restrict__ pos,
    const int* __restrict__ Hp, const int* __restrict__ Wp,
    float* __restrict__ out, int N) {
  const int t = threadIdx.x;
  const int c = t & 63;
  const int p = blockIdx.x * BQ + (t >> 6);
  const int b = blockIdx.y;
  if (p >= N) return;

  const float Wf = (float)Wp[0];
  const float Hf = (float)Hp[0];
  const float* pp = pos + ((size_t)b * N + p) * 2;
  const float px = pp[0] * (float)(Wx_ - 1) / Wf;
  const float py = pp[1] * (float)(Hx_ - 1) / Hf;

  int x0 = min(max((int)floorf(px), 0), Wx_ - 1);
  int y0 = min(max((int)floorf(py), 0), Hx_ - 1);
  const int x1 = min(x0 + 1, Wx_ - 1);
  const int y1 = min(y0 + 1, Hx_ - 1);

  const float x0f = (float)x0, x1f = (float)x1;
  const float y0f = (float)y0, y1f = (float)y1;
  const float wa = (x1f - px) * (y1f - py);
  const float wb = (x1f - px) * (py - y0f);
  const float wc = (px - x0f) * (y1f - py);
  const float wd = (px - x0f) * (py - y0f);

  const float* plane = x + (size_t)(b * C_ + c) * HW_;
  const int r0 = y0 * Wx_;
  const int r1 = y1 * Wx_;
  const float Ia = plane[r0 + x0];
  const float Ib = plane[r1 + x0];
  const float Ic = plane[r0 + x1];
  const float Id = plane[r1 + x1];

  out[((size_t)b * N + p) * C_ + c] = wa * Ia + wb * Ib + wc * Ic + wd * Id;
}

extern "C" void kernel_launch(void* const* d_in, const int* in_sizes, int n_in,
                              void* d_out, int out_size, void* d_ws, size_t ws_size,
                              hipStream_t stream) {
  const float* x = (const float*)d_in[0];
  const float* pos = (const float*)d_in[1];
  const int* Hp = (const int*)d_in[2];
  const int* Wp = (const int*)d_in[3];
  float* out = (float*)d_out;

  const int B = 16;
  const int N = in_sizes[1] / (B * 2);

  const size_t need = (size_t)B * C_ * HW_ * sizeof(unsigned short);  // 157 MB
  if (ws_size >= need) {
    unsigned short* xT = (unsigned short*)d_ws;
    dim3 tgrid(HW_ / 64, B);  // 1200 x 16
    transpose_nchw_nhwc_bf16<<<tgrid, 256, 0, stream>>>(x, xT);
    dim3 ggrid((N + 31) / 32, B);  // 32 points / block
    gather_nhwc_bf16_v2<<<ggrid, 256, 0, stream>>>(xT, pos, Hp, Wp, out, N);
  } else {
    dim3 ggrid((N + BQ - 1) / BQ, B);
    gather_nchw_direct<<<ggrid, 256, 0, stream>>>(x, pos, Hp, Wp, out, N);
  }
}

// Round 3
// 463.469 us; speedup vs baseline: 1.1293x; 1.0139x over previous
//
#include <hip/hip_runtime.h>
#include <hip/hip_bf16.h>

// Bilinear sparse interpolation, two-pass with bf16 intermediate:
//  1) transpose x [B,C,Hx,Wx] fp32 -> xT [B,Hx,Wx,C] bf16 in d_ws
//     (157 MB -- fits in the 256 MB Infinity Cache). x reads are
//     non-temporal so the streamed fp32 input does not evict xT from L3.
//  2) gather: 8 channels per thread (uint4 = 16B per corner load),
//     8 lanes per point, 32 points per 256-thread block. fp32 weights,
//     fp32 out via non-temporal float4 stores (out is never re-read).
//
// R1 evidence: NCHW gather = 7x HBM over-fetch (2.12 GB).
// R2 evidence: fp32 transpose+gather = ~245us on its own roofline.
// R3 (523us): fills dominate rocprof top-5; gather was 2B-load
//     latency-bound -> vectorized 8x + nt hints. -53.5us (-> 470us),
//     delta showed 1:1 in dur_us despite fixed ~192us poison fills.
// R5: gather is instruction-minimal (0.5 ld-instr/pt, 1KB/instr, all
//     bytes used; x0<=Wx-2 provably so no clamp slack). Remaining slack
//     is the transpose's 4B/lane loads+stores (G13): rework to f32x2 nt
//     loads + [c][hw-pair] dword LDS (stride 65, 2 lanes/bank both
//     phases = conflict-free) + uint2 stores.

constexpr int C_ = 64;
constexpr int Hx_ = 240;
constexpr int Wx_ = 320;
constexpr int HW_ = Hx_ * Wx_;

typedef float f32x4 __attribute__((ext_vector_type(4)));
typedef float f32x2 __attribute__((ext_vector_type(2)));

static __device__ __forceinline__ unsigned short f2bf_raw(float v) {
  __hip_bfloat16 h = __float2bfloat16(v);
  return *reinterpret_cast<unsigned short*>(&h);
}

// bf16 raw (packed pair in a uint) -> float
static __device__ __forceinline__ float bf_lo(unsigned int w) {
  return __uint_as_float(w << 16);
}
static __device__ __forceinline__ float bf_hi(unsigned int w) {
  return __uint_as_float(w & 0xffff0000u);
}

// ---- pass 1: NCHW fp32 -> NHWC bf16 transpose -----------------------------
// block = 256 threads, tile = 128 hw x 64 c.
// LDS layout: tl[c][hw_pair] as dwords (lo16 = even hw, hi16 = odd hw),
// row stride 65 dwords -> both phases hit each bank with exactly 2 lanes
// (free, m136).
// load : f32x2 per thread, wave = 512B contiguous nt reads
// store: repack 4 c-rows into 2 out-dwords via 16-bit merges, uint2 per
//        thread -> wave covers 4 x 128B fully-written segments
__global__ __launch_bounds__(256) void transpose_nchw_nhwc_bf16(
    const float* __restrict__ x, unsigned short* __restrict__ xT) {
  __shared__ unsigned int tl[64 * 65];  // 16.3 KB
  const int t = threadIdx.x;
  const int lane = t & 63;   // hw-pair id for load phase
  const int cg = t >> 6;     // 0..3
  const int hw0 = blockIdx.x * 128;
  const int b = blockIdx.y;

  const float* xin = x + (size_t)b * C_ * HW_ + hw0;
#pragma unroll
  for (int i = 0; i < 16; ++i) {
    const int c = i * 4 + cg;
    // non-temporal: x is streamed exactly once; keep L3 for xT
    const f32x2 v = __builtin_nontemporal_load(
        reinterpret_cast<const f32x2*>(xin + (size_t)c * HW_ + lane * 2));
    const unsigned int pk =
        (unsigned int)f2bf_raw(v.x) | ((unsigned int)f2bf_raw(v.y) << 16);
    tl[c * 65 + lane] = pk;
  }
  __syncthreads();

  // out row (one hw) = 64ch x 2B = 32 dwords = 16 uint2.
  // task e: h = hw-pair (0..63), q = uint2 col (0..15) = channels 4q..4q+3
  unsigned int* xoutd =
      (unsigned int*)(xT + (size_t)b * HW_ * C_ + (size_t)hw0 * C_);
#pragma unroll
  for (int j = 0; j < 4; ++j) {
    const int e = j * 256 + t;
    const int h = e >> 4;   // 0..63
    const int q = e & 15;   // 0..15
    const unsigned int A0 = tl[(4 * q + 0) * 65 + h];
    const unsigned int A1 = tl[(4 * q + 1) * 65 + h];
    const unsigned int A2 = tl[(4 * q + 2) * 65 + h];
    const unsigned int A3 = tl[(4 * q + 3) * 65 + h];
    uint2 lo, hi;
    lo.x = (A0 & 0xffffu) | (A1 << 16);          // hw=2h,   ch 4q,4q+1
    lo.y = (A2 & 0xffffu) | (A3 << 16);          // hw=2h,   ch 4q+2,4q+3
    hi.x = (A0 >> 16) | (A1 & 0xffff0000u);      // hw=2h+1, ch 4q,4q+1
    hi.y = (A2 >> 16) | (A3 & 0xffff0000u);      // hw=2h+1, ch 4q+2,4q+3
    *reinterpret_cast<uint2*>(xoutd + (2 * h) * 32 + 2 * q) = lo;
    *reinterpret_cast<uint2*>(xoutd + (2 * h + 1) * 32 + 2 * q) = hi;
  }
}

// ---- pass 2: gather from NHWC bf16, 8 channels / thread -------------------
// lane layout: c8 = t&7 (channels 8*c8..8*c8+7), point = t>>3 (32 pts/block)
// per corner: uint4 load = 16B = 8 bf16 channels; 4 corners in flight/thread
__global__ __launch_bounds__(256) void gather_nhwc_bf16_v2(
    const unsigned short* __restrict__ xT, const float* __restrict__ pos,
    const int* __restrict__ Hp, const int* __restrict__ Wp,
    float* __restrict__ out, int N) {
  const int t = threadIdx.x;
  const int c8 = t & 7;
  const int p = blockIdx.x * 32 + (t >> 3);
  const int b = blockIdx.y;
  if (p >= N) return;

  const float Wf = (float)Wp[0];
  const float Hf = (float)Hp[0];

  const float2 xy =
      *reinterpret_cast<const float2*>(pos + ((size_t)b * N + p) * 2);
  const float px = xy.x * (float)(Wx_ - 1) / Wf;
  const float py = xy.y * (float)(Hx_ - 1) / Hf;

  int x0 = min(max((int)floorf(px), 0), Wx_ - 1);
  int y0 = min(max((int)floorf(py), 0), Hx_ - 1);
  const int x1 = min(x0 + 1, Wx_ - 1);
  const int y1 = min(y0 + 1, Hx_ - 1);

  const float x0f = (float)x0, x1f = (float)x1;
  const float y0f = (float)y0, y1f = (float)y1;
  const float wa = (x1f - px) * (y1f - py);
  const float wb = (x1f - px) * (py - y0f);
  const float wc = (px - x0f) * (y1f - py);
  const float wd = (px - x0f) * (py - y0f);

  const unsigned short* bb = xT + (size_t)b * (size_t)(HW_ * C_);
  const int r0 = y0 * Wx_;
  const int r1 = y1 * Wx_;
  const int co = c8 * 8;  // channel offset within the 64-ch pixel record

  const uint4 va = *reinterpret_cast<const uint4*>(bb + (r0 + x0) * C_ + co);
  const uint4 vb = *reinterpret_cast<const uint4*>(bb + (r1 + x0) * C_ + co);
  const uint4 vc = *reinterpret_cast<const uint4*>(bb + (r0 + x1) * C_ + co);
  const uint4 vd = *reinterpret_cast<const uint4*>(bb + (r1 + x1) * C_ + co);

  f32x4 o0, o1;
  o0.x = wa * bf_lo(va.x) + wb * bf_lo(vb.x) + wc * bf_lo(vc.x) + wd * bf_lo(vd.x);
  o0.y = wa * bf_hi(va.x) + wb * bf_hi(vb.x) + wc * bf_hi(vc.x) + wd * bf_hi(vd.x);
  o0.z = wa * bf_lo(va.y) + wb * bf_lo(vb.y) + wc * bf_lo(vc.y) + wd * bf_lo(vd.y);
  o0.w = wa * bf_hi(va.y) + wb * bf_hi(vb.y) + wc * bf_hi(vc.y) + wd * bf_hi(vd.y);
  o1.x = wa * bf_lo(va.z) + wb * bf_lo(vb.z) + wc * bf_lo(vc.z) + wd * bf_lo(vd.z);
  o1.y = wa * bf_hi(va.z) + wb * bf_hi(vb.z) + wc * bf_hi(vc.z) + wd * bf_hi(vd.z);
  o1.z = wa * bf_lo(va.w) + wb * bf_lo(vb.w) + wc * bf_lo(vc.w) + wd * bf_lo(vd.w);
  o1.w = wa * bf_hi(va.w) + wb * bf_hi(vb.w) + wc * bf_hi(vc.w) + wd * bf_hi(vd.w);

  float* op = out + ((size_t)b * N + p) * C_ + co;
  // non-temporal: out is write-once, never re-read; keep L3 for xT
  __builtin_nontemporal_store(o0, reinterpret_cast<f32x4*>(op));
  __builtin_nontemporal_store(o1, reinterpret_cast<f32x4*>(op) + 1);
}

// ---- fallback (direct NCHW gather) if ws too small ------------------------
#define BQ 4  // points per block

__global__ __launch_bounds__(256) void gather_nchw_direct(
    const float* __restrict__ x, const float* __restrict__ pos,
    const int* __restrict__ Hp, const int* __restrict__ Wp,
    float* __restrict__ out, int N) {
  const int t = threadIdx.x;
  const int c = t & 63;
  const int p = blockIdx.x * BQ + (t >> 6);
  const int b = blockIdx.y;
  if (p >= N) return;

  const float Wf = (float)Wp[0];
  const float Hf = (float)Hp[0];
  const float* pp = pos + ((size_t)b * N + p) * 2;
  const float px = pp[0] * (float)(Wx_ - 1) / Wf;
  const float py = pp[1] * (float)(Hx_ - 1) / Hf;

  int x0 = min(max((int)floorf(px), 0), Wx_ - 1);
  int y0 = min(max((int)floorf(py), 0), Hx_ - 1);
  const int x1 = min(x0 + 1, Wx_ - 1);
  const int y1 = min(y0 + 1, Hx_ - 1);

  const float x0f = (float)x0, x1f = (float)x1;
  const float y0f = (float)y0, y1f = (float)y1;
  const float wa = (x1f - px) * (y1f - py);
  const float wb = (x1f - px) * (py - y0f);
  const float wc = (px - x0f) * (y1f - py);
  const float wd = (px - x0f) * (py - y0f);

  const float* plane = x + (size_t)(b * C_ + c) * HW_;
  const int r0 = y0 * Wx_;
  const int r1 = y1 * Wx_;
  const float Ia = plane[r0 + x0];
  const float Ib = plane[r1 + x0];
  const float Ic = plane[r0 + x1];
  const float Id = plane[r1 + x1];

  out[((size_t)b * N + p) * C_ + c] = wa * Ia + wb * Ib + wc * Ic + wd * Id;
}

extern "C" void kernel_launch(void* const* d_in, const int* in_sizes, int n_in,
                              void* d_out, int out_size, void* d_ws, size_t ws_size,
                              hipStream_t stream) {
  const float* x = (const float*)d_in[0];
  const float* pos = (const float*)d_in[1];
  const int* Hp = (const int*)d_in[2];
  const int* Wp = (const int*)d_in[3];
  float* out = (float*)d_out;

  const int B = 16;
  const int N = in_sizes[1] / (B * 2);

  const size_t need = (size_t)B * C_ * HW_ * sizeof(unsigned short);  // 157 MB
  if (ws_size >= need) {
    unsigned short* xT = (unsigned short*)d_ws;
    dim3 tgrid(HW_ / 128, B);  // 600 x 16
    transpose_nchw_nhwc_bf16<<<tgrid, 256, 0, stream>>>(x, xT);
    dim3 ggrid((N + 31) / 32, B);  // 32 points / block
    gather_nhwc_bf16_v2<<<ggrid, 256, 0, stream>>>(xT, pos, Hp, Wp, out, N);
  } else {
    dim3 ggrid((N + BQ - 1) / BQ, B);
    gather_nchw_direct<<<ggrid, 256, 0, stream>>>(x, pos, Hp, Wp, out, N);
  }
}